// Round 4
// baseline (226.397 us; speedup 1.0000x reference)
//
#include <hip/hip_runtime.h>
#include <math.h>

#define DIM      64
#define N_MEM    32
#define N_ENTITY 500000
#define N_REL    32
#define N_ITEM   10000
#define HOPS     2
#define BATCH    4096
#define HIST     50

typedef float4 f4;

// ---------------------------------------------------------------------------
// Stage 1 (fully fused): ONE wave per item handles BOTH hops plus the item
// row and writes folded[i] directly. The 32 relation dots (8 KB L1-resident
// table) are computed in-wave: lane l loads 8 f4s of relation row l>>1,
// pair-reduces, and rdot[r] is routed to consumers via __shfl. This removes
// the separate rdot kernel and its launch/dependency bubble.
// ---------------------------------------------------------------------------
__global__ __launch_bounds__(256) void ripple_stage1(
    const float* __restrict__ W_w,
    const float* __restrict__ W_b,
    const int*   __restrict__ heads,
    const int*   __restrict__ relations,
    const int*   __restrict__ tails,
    const float* __restrict__ entity_emb,
    const float* __restrict__ relation_emb,
    const int*   __restrict__ item_ids,
    float*       __restrict__ folded)    // [N_ITEM][DIM]
{
    const int wave = (blockIdx.x * blockDim.x + threadIdx.x) >> 6;
    const int lane = threadIdx.x & 63;
    if (wave >= N_ITEM) return;
    const int i = wave;
    const int g = lane >> 4;
    const int p = lane & 15;

    const f4* __restrict__ E4 = (const f4*)entity_emb;
    const f4* __restrict__ W4 = (const f4*)W_w;
    const f4 wh = W4[p];
    const f4 wt = W4[32 + p];
    const float bias = W_b[0];

    // ---- Indices for BOTH hops, one instruction per array:
    // lanes 0..31 -> hop0 memory m=lane; lanes 32..63 -> hop1 memory m=lane-32.
    const int m    = lane & 31;
    const int hsel = lane >> 5;
    const size_t idxoff = (size_t)hsel * ((size_t)N_ITEM * N_MEM)
                        + (size_t)i * N_MEM + m;
    const int hidx = heads[idxoff];
    const int ridx = relations[idxoff];
    const int tidx = tails[idxoff];

    // ---- In-wave rdot: lane l handles half of relation row (l>>1).
    // 8 L1-hit f4 loads + 4-FMA chains + one pair reduce.
    {
    }
    const int rrow = lane >> 1;
    const int rc   = lane & 1;
    const f4* __restrict__ R4 = (const f4*)relation_emb;
    float rpart = 0.f;
#pragma unroll
    for (int q = 0; q < 8; ++q) {
        const f4 rv = R4[(size_t)rrow * 16 + rc * 8 + q];
        const f4 wv = W4[16 + rc * 8 + q];
        rpart += rv.x * wv.x + rv.y * wv.y + rv.z * wv.z + rv.w * wv.w;
    }
    rpart += __shfl_xor(rpart, 1, 64);          // lanes 2r,2r+1 hold rdot[r]
    const float lrl = __shfl(rpart, ridx << 1, 64);  // this lane's relation dot

    const f4 item = E4[(size_t)item_ids[i] * 16 + p];

    f4 accs[2];
#pragma unroll
    for (int h = 0; h < 2; ++h) {
        // distribute: lane (g,p) handles memories m = 4k+g of hop h
        int hi[8], ti[8]; float lrv[8];
#pragma unroll
        for (int k = 0; k < 8; ++k) {
            const int src = h * 32 + 4 * k + g;
            hi[k]  = __shfl(hidx, src, 64);
            ti[k]  = __shfl(tidx, src, 64);
            lrv[k] = __shfl(lrl,  src, 64);
        }

        // 16 f4 row-gathers in flight (head + tail)
        f4 he[8], te[8];
#pragma unroll
        for (int k = 0; k < 8; ++k) he[k] = E4[(size_t)hi[k] * 16 + p];
#pragma unroll
        for (int k = 0; k < 8; ++k) te[k] = E4[(size_t)ti[k] * 16 + p];

        // 16-lane reduces (4 memories in parallel), sigmoid+exp
        float e[8];
        float se = 0.f;
#pragma unroll
        for (int k = 0; k < 8; ++k) {
            float v = he[k].x * wh.x + he[k].y * wh.y + he[k].z * wh.z + he[k].w * wh.w
                    + te[k].x * wt.x + te[k].y * wt.y + te[k].z * wt.z + te[k].w * wt.w;
            v += __shfl_xor(v, 1, 64);
            v += __shfl_xor(v, 2, 64);
            v += __shfl_xor(v, 4, 64);
            v += __shfl_xor(v, 8, 64);
            const float logit = v + lrv[k] + bias;
            const float sig   = 1.f / (1.f + __expf(-logit));
            const float ex    = __expf(sig);
            e[k] = ex;
            se += ex;
        }
        se += __shfl_xor(se, 16, 64);
        se += __shfl_xor(se, 32, 64);
        const float inv = 1.f / se;

        // weighted tail sum from registers
        f4 acc = {0.f, 0.f, 0.f, 0.f};
#pragma unroll
        for (int k = 0; k < 8; ++k) {
            const float w = e[k] * inv;
            acc.x += w * te[k].x;
            acc.y += w * te[k].y;
            acc.z += w * te[k].z;
            acc.w += w * te[k].w;
        }
        acc.x += __shfl_xor(acc.x, 16, 64);
        acc.x += __shfl_xor(acc.x, 32, 64);
        acc.y += __shfl_xor(acc.y, 16, 64);
        acc.y += __shfl_xor(acc.y, 32, 64);
        acc.z += __shfl_xor(acc.z, 16, 64);
        acc.z += __shfl_xor(acc.z, 32, 64);
        acc.w += __shfl_xor(acc.w, 16, 64);
        acc.w += __shfl_xor(acc.w, 32, 64);
        accs[h] = acc;
    }

    if (g == 0) {
        f4 r;
        r.x = item.x + accs[0].x + accs[1].x;   // (item + hop0) + hop1 order
        r.y = item.y + accs[0].y + accs[1].y;
        r.z = item.z + accs[0].z + accs[1].z;
        r.w = item.w + accs[0].w + accs[1].w;
        ((f4*)folded)[(size_t)i * 16 + p] = r;
    }
}

// ---------------------------------------------------------------------------
// Stage 2: one wave per batch row; 50 history indices loaded once (one instr)
// and redistributed via __shfl.
// ---------------------------------------------------------------------------
__global__ __launch_bounds__(256) void ripple_stage2(
    const float* __restrict__ entity_emb,
    const int*   __restrict__ records_idx,
    const int*   __restrict__ items,
    const float* __restrict__ folded,
    float*       __restrict__ out)
{
    const int wave = (blockIdx.x * blockDim.x + threadIdx.x) >> 6;
    const int lane = threadIdx.x & 63;
    if (wave >= BATCH) return;
    const int b = wave;
    const int g = lane >> 4;
    const int p = lane & 15;

    const f4* __restrict__ A4 = (const f4*)folded;
    const f4* __restrict__ E4 = (const f4*)entity_emb;

    const int rb = b * HIST;
    const int lc = lane < HIST ? lane : (HIST - 1);
    const int idxl = records_idx[rb + lc];     // lane j<50 holds index j

    f4 user = {0.f, 0.f, 0.f, 0.f};
#pragma unroll
    for (int k = 0; k < 13; ++k) {
        const int   j  = 4 * k + g;
        const int   js = j < HIST ? j : 0;
        const float w  = j < HIST ? 1.f : 0.f;
        const int  idx = __shfl(idxl, js, 64);
        const f4 r = A4[(size_t)idx * 16 + p];
        user.x += w * r.x;
        user.y += w * r.y;
        user.z += w * r.z;
        user.w += w * r.w;
    }
    user.x += __shfl_xor(user.x, 16, 64);
    user.x += __shfl_xor(user.x, 32, 64);
    user.y += __shfl_xor(user.y, 16, 64);
    user.y += __shfl_xor(user.y, 32, 64);
    user.z += __shfl_xor(user.z, 16, 64);
    user.z += __shfl_xor(user.z, 32, 64);
    user.w += __shfl_xor(user.w, 16, 64);
    user.w += __shfl_xor(user.w, 32, 64);

    const f4 pair = E4[(size_t)items[b] * 16 + p];
    float dot = user.x * pair.x + user.y * pair.y + user.z * pair.z + user.w * pair.w;
    dot += __shfl_xor(dot, 1, 64);
    dot += __shfl_xor(dot, 2, 64);
    dot += __shfl_xor(dot, 4, 64);
    dot += __shfl_xor(dot, 8, 64);
    if (lane == 0) out[b] = 1.f / (1.f + __expf(-dot));
}

extern "C" void kernel_launch(void* const* d_in, const int* in_sizes, int n_in,
                              void* d_out, int out_size, void* d_ws, size_t ws_size,
                              hipStream_t stream) {
    const float* entity_emb   = (const float*)d_in[0];
    const float* relation_emb = (const float*)d_in[1];
    const float* W_w          = (const float*)d_in[2];
    const float* W_b          = (const float*)d_in[3];
    const int*   item_ids     = (const int*)d_in[4];
    const int*   heads        = (const int*)d_in[5];
    const int*   relations    = (const int*)d_in[6];
    const int*   tails        = (const int*)d_in[7];
    const int*   records_idx  = (const int*)d_in[8];
    const int*   items        = (const int*)d_in[9];
    float* out = (float*)d_out;

    float* folded = (float*)d_ws;                          // 2.56 MB

    const int blocks1 = (N_ITEM + 3) / 4;      // one wave per item, 4 waves/block
    ripple_stage1<<<blocks1, 256, 0, stream>>>(W_w, W_b, heads, relations, tails,
                                               entity_emb, relation_emb, item_ids,
                                               folded);

    const int blocks2 = (BATCH + 3) / 4;
    ripple_stage2<<<blocks2, 256, 0, stream>>>(entity_emb, records_idx, items,
                                               folded, out);
}